// Round 5
// baseline (5426.178 us; speedup 1.0000x reference)
//
#include <hip/hip_runtime.h>
#include <stdint.h>
#include <cstdio>

#define B   256
#define T   1024
#define FIN 64
#define H   128
#define G4  512   // 4*H

typedef float vf32 __attribute__((ext_vector_type(32)));

// Register-file element access: n must be an integer constant expression.
// Ternary folds at compile time -> single extract/insertelement. This is the
// fix for R4: alloca'd float w[128] was demoted to scratch (VGPR_Count=76,
// ~4000 cyc/step scratch-BW-bound); SSA vector values cannot be demoted.
#define WG(n)    ((n) < 32 ? wa[(n) & 31] : (n) < 64 ? wb[(n) & 31] : (n) < 96 ? wc[(n) & 31] : wd[(n) & 31])
#define WS(n, v) do { if ((n) < 32) wa[(n) & 31] = (v); else if ((n) < 64) wb[(n) & 31] = (v); \
                      else if ((n) < 96) wc[(n) & 31] = (v); else wd[(n) & 31] = (v); } while (0)
#define WLD4(n)  { float4 t4 = *(const float4*)(wp + (n)); \
                   WS((n)+0, t4.x); WS((n)+1, t4.y); WS((n)+2, t4.z); WS((n)+3, t4.w); }
#define WLD16(n) WLD4(n) WLD4((n)+4) WLD4((n)+8) WLD4((n)+12)
#define WLD64(n) WLD16(n) WLD16((n)+16) WLD16((n)+32) WLD16((n)+48)

#define RL(v, q) __int_as_float(__builtin_amdgcn_readlane(__float_as_int(v), (q)))

// ----------------------------------------------------------------------------
// prep: transpose W_ih -> WT[k][j], bias sums, zero recurrent states
// ----------------------------------------------------------------------------
__global__ void prep_kernel(const float* __restrict__ W_ih0,
                            const float* __restrict__ b_ih0, const float* __restrict__ b_hh0,
                            const float* __restrict__ W_ih1,
                            const float* __restrict__ b_ih1, const float* __restrict__ b_hh1,
                            float* __restrict__ WT0, float* __restrict__ WT1,
                            float* __restrict__ bsum0, float* __restrict__ bsum1,
                            float* __restrict__ states /* 4*B*H */)
{
    int idx = blockIdx.x * blockDim.x + threadIdx.x;
    int n   = gridDim.x * blockDim.x;
    for (int i = idx; i < H * G4; i += n) { int k = i / G4, j = i % G4; WT1[i] = W_ih1[j * H + k]; }
    for (int i = idx; i < FIN * G4; i += n) { int k = i / G4, j = i % G4; WT0[i] = W_ih0[j * FIN + k]; }
    for (int i = idx; i < G4; i += n) { bsum0[i] = b_ih0[i] + b_hh0[i]; bsum1[i] = b_ih1[i] + b_hh1[i]; }
    for (int i = idx; i < 4 * B * H; i += n) states[i] = 0.f;
}

// ----------------------------------------------------------------------------
// gx GEMM: gx[tcl][b][j] = bias[j] + sum_k X[b, toff+tcl, k] * WT[k][j]
// 512 threads = 512 columns; 16 rows per block. Weights in SSA vector regs.
// ----------------------------------------------------------------------------
#define GK4(k) { \
    float4 v0 = *(const float4*)(x0 + (k)); \
    float4 v1 = *(const float4*)(x1 + (k)); \
    float4 v2 = *(const float4*)(x2 + (k)); \
    float4 v3 = *(const float4*)(x3 + (k)); \
    a0 = fmaf(v0.x, WG(k), a0); a0 = fmaf(v0.y, WG((k)+1), a0); a0 = fmaf(v0.z, WG((k)+2), a0); a0 = fmaf(v0.w, WG((k)+3), a0); \
    a1 = fmaf(v1.x, WG(k), a1); a1 = fmaf(v1.y, WG((k)+1), a1); a1 = fmaf(v1.z, WG((k)+2), a1); a1 = fmaf(v1.w, WG((k)+3), a1); \
    a2 = fmaf(v2.x, WG(k), a2); a2 = fmaf(v2.y, WG((k)+1), a2); a2 = fmaf(v2.z, WG((k)+2), a2); a2 = fmaf(v2.w, WG((k)+3), a2); \
    a3 = fmaf(v3.x, WG(k), a3); a3 = fmaf(v3.y, WG((k)+1), a3); a3 = fmaf(v3.z, WG((k)+2), a3); a3 = fmaf(v3.w, WG((k)+3), a3); }
#define GK16(k) GK4(k) GK4((k)+4) GK4((k)+8) GK4((k)+12)
#define GK64(k) GK16(k) GK16((k)+16) GK16((k)+32) GK16((k)+48)

template<int K>
__global__ __launch_bounds__(512, 1)
void gemm_gx(const float* __restrict__ X, long sB, long sT, int toff,
             const float* __restrict__ WT, const float* __restrict__ bsum,
             float* __restrict__ gx, int Tc)
{
    const int j    = threadIdx.x;
    const int m0   = blockIdx.x * 16;
    const int b    = m0 / Tc;
    const int tcl0 = m0 % Tc;

    vf32 wa, wb, wc, wd;
    {
        const float* __restrict__ wp0 = WT + j;
        // strided gather of column j: w[k] = WT[k*G4 + j]
#define CLD(n) WS(n, wp0[(long)(n) * G4]);
#define CLD4(n)  CLD(n) CLD((n)+1) CLD((n)+2) CLD((n)+3)
#define CLD16(n) CLD4(n) CLD4((n)+4) CLD4((n)+8) CLD4((n)+12)
#define CLD64(n) CLD16(n) CLD16((n)+16) CLD16((n)+32) CLD16((n)+48)
        CLD64(0)
        if constexpr (K == 128) { CLD64(64) }
#undef CLD
#undef CLD4
#undef CLD16
#undef CLD64
    }
    const float bj = bsum[j];

    const float* __restrict__ xb = X + (long)b * sB + (long)(toff + tcl0) * sT;
    float* __restrict__ gb = gx + (long)tcl0 * (B * G4) + (long)b * G4 + j;
    const long gstride = (long)B * G4;

#pragma unroll 1
    for (int r = 0; r < 16; r += 4) {
        float a0 = bj, a1 = bj, a2 = bj, a3 = bj;
        const float* __restrict__ x0 = xb + (long)(r + 0) * sT;
        const float* __restrict__ x1 = xb + (long)(r + 1) * sT;
        const float* __restrict__ x2 = xb + (long)(r + 2) * sT;
        const float* __restrict__ x3 = xb + (long)(r + 3) * sT;
        GK64(0)
        if constexpr (K == 128) { GK64(64) }
        gb[(long)(r + 0) * gstride] = a0;
        gb[(long)(r + 1) * gstride] = a1;
        gb[(long)(r + 2) * gstride] = a2;
        gb[(long)(r + 3) * gstride] = a3;
    }
}

// ----------------------------------------------------------------------------
// LSTM scan. One block per batch element (grid=256 = 1 block/CU), 512 threads.
// Thread tid owns gate row tid (full 128-wide dot). Weights in SSA vector
// registers (wa..wd = 128 VGPRs). h broadcast via readlane with literal lane
// indices. 4 accumulators break the dependent-fmac chain.
// ----------------------------------------------------------------------------
#define DOT1(q, ga, gb_) { float a0_ = RL(h0, q); float a1_ = RL(h1, q); \
                           ga  = fmaf(a0_, WG(q),        ga); \
                           gb_ = fmaf(a1_, WG((q)+64),   gb_); }
#define DOT2(q)  DOT1(q, g0, g1) DOT1((q)+1, g2, g3)
#define DOT8(q)  DOT2(q) DOT2((q)+2) DOT2((q)+4) DOT2((q)+6)
#define DOT32(q) DOT8(q) DOT8((q)+8) DOT8((q)+16) DOT8((q)+24)

__global__ __launch_bounds__(512, 1)
void lstm_scan(const float* __restrict__ gx, const float* __restrict__ Whh,
               float* __restrict__ h_state, float* __restrict__ c_state,
               float* __restrict__ h1c,     /* null for layer 1 */
               float* __restrict__ h2last,  /* null for layer 0 */
               int Tc, int storeLast)
{
    __shared__ float h_sh[H];
    __shared__ float gates[G4];

    const int tid  = threadIdx.x;   // row index in [0, 512)
    const int b    = blockIdx.x;
    const int lane = tid & 63;

    vf32 wa, wb, wc, wd;
    {
        const float* __restrict__ wp = Whh + (long)tid * H;
        WLD64(0) WLD64(64)
    }

    float c = 0.f;
    if (tid < H) { h_sh[tid] = h_state[b * H + tid]; c = c_state[b * H + tid]; }
    __syncthreads();
    float h0 = h_sh[lane];
    float h1 = h_sh[64 + lane];

    const long gstride = (long)B * G4;
    const float* __restrict__ gxp = gx + (long)b * G4 + tid;
    float gc = gxp[0];
    float gn = (Tc > 1) ? gxp[gstride] : 0.f;

    for (int t = 0; t < Tc; ++t) {
        float gn2 = (t + 2 < Tc) ? gxp[(long)(t + 2) * gstride] : 0.f;

        float g0 = gc, g1 = 0.f, g2 = 0.f, g3 = 0.f;
        DOT32(0) DOT32(32)
        float g = (g0 + g1) + (g2 + g3);

        // rows [0,256) = i,f (sigmoid); [256,384) = g (tanh); [384,512) = o (sigmoid)
        float act = (tid < 2 * H || tid >= 3 * H) ? 1.f / (1.f + expf(-g)) : tanhf(g);
        gates[tid] = act;
        __syncthreads();

        if (tid < H) {
            float iv = gates[tid], fv = gates[H + tid], gv = gates[2 * H + tid], ov = gates[3 * H + tid];
            c = fmaf(fv, c, iv * gv);
            float hn = ov * tanhf(c);
            h_sh[tid] = hn;
            if (h1c) h1c[(long)b * Tc * H + (long)t * H + tid] = hn;
            if (storeLast && t == Tc - 1) h2last[b * H + tid] = hn;
        }
        __syncthreads();
        h0 = h_sh[lane];
        h1 = h_sh[64 + lane];
        gc = gn; gn = gn2;
    }

    if (tid < H) { h_state[b * H + tid] = h_sh[tid]; c_state[b * H + tid] = c; }
}

// ----------------------------------------------------------------------------
// Dropout: JAX threefry2x32, jax_threefry_partitionable=True (default since
// jax 0.4.36): counter (0, e), bits = y0 ^ y1, key (0, 42).
// ----------------------------------------------------------------------------
__device__ __forceinline__ uint32_t rotl32(uint32_t x, int r) { return (x << r) | (x >> (32 - r)); }

__global__ void dropout_kernel(const float* __restrict__ h2last, float* __restrict__ h2drop)
{
    int e = blockIdx.x * blockDim.x + threadIdx.x;
    if (e >= B * H) return;
    const uint32_t k0 = 0u, k1 = 42u, k2 = 0u ^ 42u ^ 0x1BD11BDAu;
    uint32_t x0 = 0u;
    uint32_t x1 = (uint32_t)e;
    x0 += k0; x1 += k1;
#define RG(ra,rb,rc,rd,ka,kb,inc) \
    x0 += x1; x1 = rotl32(x1, ra); x1 ^= x0; \
    x0 += x1; x1 = rotl32(x1, rb); x1 ^= x0; \
    x0 += x1; x1 = rotl32(x1, rc); x1 ^= x0; \
    x0 += x1; x1 = rotl32(x1, rd); x1 ^= x0; \
    x0 += ka; x1 += kb + inc;
    RG(13,15,26, 6, k1, k2, 1u)
    RG(17,29,16,24, k2, k0, 2u)
    RG(13,15,26, 6, k0, k1, 3u)
    RG(17,29,16,24, k1, k2, 4u)
    RG(13,15,26, 6, k2, k0, 5u)
#undef RG
    uint32_t bits = x0 ^ x1;
    float u = __uint_as_float((bits >> 9) | 0x3f800000u) - 1.0f;
    float a = h2last[e];
    h2drop[e] = (u >= 0.3f) ? (a / 0.7f) : 0.0f;
}

// ----------------------------------------------------------------------------
// Head: out[b][n] = b_out[n] + sum_u h2drop[b][u] * W_out[n][u]
// ----------------------------------------------------------------------------
__global__ void out_kernel(const float* __restrict__ h2drop, const float* __restrict__ W_out,
                           const float* __restrict__ b_out, float* __restrict__ out)
{
    int i = blockIdx.x * blockDim.x + threadIdx.x;
    if (i >= B * 2) return;
    int bb = i >> 1, n = i & 1;
    float acc = b_out[n];
    const float* __restrict__ hp = h2drop + (long)bb * H;
    const float* __restrict__ wp = W_out + (long)n * H;
#pragma unroll 4
    for (int u = 0; u < H; ++u) acc = fmaf(hp[u], wp[u], acc);
    out[i] = acc;
}

// ----------------------------------------------------------------------------
extern "C" void kernel_launch(void* const* d_in, const int* in_sizes, int n_in,
                              void* d_out, int out_size, void* d_ws, size_t ws_size,
                              hipStream_t stream)
{
    const float* x     = (const float*)d_in[0];
    const float* W_ih0 = (const float*)d_in[1];
    const float* W_hh0 = (const float*)d_in[2];
    const float* b_ih0 = (const float*)d_in[3];
    const float* b_hh0 = (const float*)d_in[4];
    const float* W_ih1 = (const float*)d_in[5];
    const float* W_hh1 = (const float*)d_in[6];
    const float* b_ih1 = (const float*)d_in[7];
    const float* b_hh1 = (const float*)d_in[8];
    const float* W_out = (const float*)d_in[9];
    const float* b_out = (const float*)d_in[10];
    float* out = (float*)d_out;

    char* ws = (char*)d_ws;
    size_t off = 0;
    auto alloc = [&](size_t bytes) { void* p = ws + off; off += (bytes + 255) & ~255ull; return p; };

    float* WT0    = (float*)alloc((size_t)FIN * G4 * 4);
    float* WT1    = (float*)alloc((size_t)H * G4 * 4);
    float* bsum0  = (float*)alloc((size_t)G4 * 4);
    float* bsum1  = (float*)alloc((size_t)G4 * 4);
    float* states = (float*)alloc((size_t)4 * B * H * 4);
    float* h0s = states, *c0s = states + B * H, *h1s = states + 2 * B * H, *c1s = states + 3 * B * H;
    float* h2last = (float*)alloc((size_t)B * H * 4);
    float* h2drop = (float*)alloc((size_t)B * H * 4);

    size_t fixed = off;
    int Tc = 16;
    const int cands[7] = {1024, 512, 256, 128, 64, 32, 16};
    for (int ci = 0; ci < 7; ++ci) {
        size_t need = fixed + (size_t)cands[ci] * ((size_t)B * H * 4 + (size_t)B * G4 * 4) + 8192;
        if (need <= ws_size) { Tc = cands[ci]; break; }
    }
    float* h1c = (float*)alloc((size_t)B * Tc * H * 4);
    float* gxb = (float*)alloc((size_t)Tc * B * G4 * 4);

    fprintf(stderr, "[kernel_launch] ws_size=%zu fixed=%zu Tc=%d total_used=%zu\n",
            ws_size, fixed, Tc, off);

    prep_kernel<<<512, 256, 0, stream>>>(W_ih0, b_ih0, b_hh0, W_ih1, b_ih1, b_hh1,
                                         WT0, WT1, bsum0, bsum1, states);

    const int nch = T / Tc;
    for (int c = 0; c < nch; ++c) {
        int t0 = c * Tc;
        gemm_gx<FIN><<<(B * Tc) / 16, 512, 0, stream>>>(x, (long)T * FIN, (long)FIN, t0,
                                                        WT0, bsum0, gxb, Tc);
        lstm_scan<<<B, 512, 0, stream>>>(gxb, W_hh0, h0s, c0s, h1c, nullptr, Tc, 0);
        gemm_gx<H><<<(B * Tc) / 16, 512, 0, stream>>>(h1c, (long)Tc * H, (long)H, 0,
                                                      WT1, bsum1, gxb, Tc);
        lstm_scan<<<B, 512, 0, stream>>>(gxb, W_hh1, h1s, c1s, nullptr, h2last, Tc,
                                         (t0 + Tc == T) ? 1 : 0);
    }

    dropout_kernel<<<128, 256, 0, stream>>>(h2last, h2drop);
    out_kernel<<<2, 256, 0, stream>>>(h2drop, W_out, b_out, out);
}

// Round 6
// 4648.951 us; speedup vs baseline: 1.1672x; 1.1672x over previous
//
#include <hip/hip_runtime.h>
#include <stdint.h>
#include <cstdio>

#define B   256
#define T   1024
#define FIN 64
#define H   128
#define G4  512   // 4*H

typedef float vf32 __attribute__((ext_vector_type(32)));
typedef float vf16 __attribute__((ext_vector_type(16)));

#define RL(v, q) __int_as_float(__builtin_amdgcn_readlane(__float_as_int(v), (q)))

// 64-float register bank in two SSA vectors (wa, wb). Literal indices only.
#define WG2(n)    ((n) < 32 ? wa[(n) & 31] : wb[(n) & 31])
#define WS2(n, v) do { if ((n) < 32) wa[(n) & 31] = (v); else wb[(n) & 31] = (v); } while (0)

// ----------------------------------------------------------------------------
// prep: transpose W_ih -> WT[k][j], bias sums, zero recurrent states
// ----------------------------------------------------------------------------
__global__ void prep_kernel(const float* __restrict__ W_ih0,
                            const float* __restrict__ b_ih0, const float* __restrict__ b_hh0,
                            const float* __restrict__ W_ih1,
                            const float* __restrict__ b_ih1, const float* __restrict__ b_hh1,
                            float* __restrict__ WT0, float* __restrict__ WT1,
                            float* __restrict__ bsum0, float* __restrict__ bsum1,
                            float* __restrict__ states /* 4*B*H */)
{
    int idx = blockIdx.x * blockDim.x + threadIdx.x;
    int n   = gridDim.x * blockDim.x;
    for (int i = idx; i < H * G4; i += n) { int k = i / G4, j = i % G4; WT1[i] = W_ih1[j * H + k]; }
    for (int i = idx; i < FIN * G4; i += n) { int k = i / G4, j = i % G4; WT0[i] = W_ih0[j * FIN + k]; }
    for (int i = idx; i < G4; i += n) { bsum0[i] = b_ih0[i] + b_hh0[i]; bsum1[i] = b_ih1[i] + b_hh1[i]; }
    for (int i = idx; i < 4 * B * H; i += n) states[i] = 0.f;
}

// ----------------------------------------------------------------------------
// gx GEMM: gx[tcl][b][j] = bias[j] + sum_k X[b, toff+tcl, k] * WT[k][j]
// 512 threads = 512 columns; 16 rows per block. K processed in 64-wide halves
// so only 64 weights are live at once (fits the register budget); 16
// accumulators persist across halves in a vf16. waves_per_eu(2,2): 8 waves/CU,
// 256-VGPR budget -> no spill.
// ----------------------------------------------------------------------------
#define CLDW(n) WS2(n, wp0[(long)(n) * G4]);
#define CLDW4(n)  CLDW(n) CLDW((n)+1) CLDW((n)+2) CLDW((n)+3)
#define CLDW16(n) CLDW4(n) CLDW4((n)+4) CLDW4((n)+8) CLDW4((n)+12)
#define CLDW64    CLDW16(0) CLDW16(16) CLDW16(32) CLDW16(48)

#define GK4R(k, r0) { \
    float4 v0 = *(const float4*)(x0 + (k)); \
    float4 v1 = *(const float4*)(x1 + (k)); \
    float4 v2 = *(const float4*)(x2 + (k)); \
    float4 v3 = *(const float4*)(x3 + (k)); \
    acc[(r0)+0] = fmaf(v0.x, WG2(k), acc[(r0)+0]); acc[(r0)+0] = fmaf(v0.y, WG2((k)+1), acc[(r0)+0]); \
    acc[(r0)+0] = fmaf(v0.z, WG2((k)+2), acc[(r0)+0]); acc[(r0)+0] = fmaf(v0.w, WG2((k)+3), acc[(r0)+0]); \
    acc[(r0)+1] = fmaf(v1.x, WG2(k), acc[(r0)+1]); acc[(r0)+1] = fmaf(v1.y, WG2((k)+1), acc[(r0)+1]); \
    acc[(r0)+1] = fmaf(v1.z, WG2((k)+2), acc[(r0)+1]); acc[(r0)+1] = fmaf(v1.w, WG2((k)+3), acc[(r0)+1]); \
    acc[(r0)+2] = fmaf(v2.x, WG2(k), acc[(r0)+2]); acc[(r0)+2] = fmaf(v2.y, WG2((k)+1), acc[(r0)+2]); \
    acc[(r0)+2] = fmaf(v2.z, WG2((k)+2), acc[(r0)+2]); acc[(r0)+2] = fmaf(v2.w, WG2((k)+3), acc[(r0)+2]); \
    acc[(r0)+3] = fmaf(v3.x, WG2(k), acc[(r0)+3]); acc[(r0)+3] = fmaf(v3.y, WG2((k)+1), acc[(r0)+3]); \
    acc[(r0)+3] = fmaf(v3.z, WG2((k)+2), acc[(r0)+3]); acc[(r0)+3] = fmaf(v3.w, WG2((k)+3), acc[(r0)+3]); }
#define GK16R(k, r0) GK4R(k, r0) GK4R((k)+4, r0) GK4R((k)+8, r0) GK4R((k)+12, r0)
#define GK64R(r0)    GK16R(0, r0) GK16R(16, r0) GK16R(32, r0) GK16R(48, r0)

#define GGRP(r0, xoff) { \
    const float* __restrict__ x0 = xb + (long)((r0)+0) * sT + (xoff); \
    const float* __restrict__ x1 = xb + (long)((r0)+1) * sT + (xoff); \
    const float* __restrict__ x2 = xb + (long)((r0)+2) * sT + (xoff); \
    const float* __restrict__ x3 = xb + (long)((r0)+3) * sT + (xoff); \
    GK64R(r0) }

template<int K>
__global__ __launch_bounds__(512) __attribute__((amdgpu_waves_per_eu(2, 2)))
void gemm_gx(const float* __restrict__ X, long sB, long sT, int toff,
             const float* __restrict__ WT, const float* __restrict__ bsum,
             float* __restrict__ gx, int Tc)
{
    const int j    = threadIdx.x;
    const int m0   = blockIdx.x * 16;
    const int b    = m0 / Tc;
    const int tcl0 = m0 % Tc;

    const float bj = bsum[j];
    vf16 acc;
#pragma unroll
    for (int r = 0; r < 16; ++r) acc[r] = bj;

    const float* __restrict__ xb = X + (long)b * sB + (long)(toff + tcl0) * sT;
    float* __restrict__ gb = gx + (long)tcl0 * (B * G4) + (long)b * G4 + j;
    const long gstride = (long)B * G4;

    {   // k-half 0: k in [0,64)
        vf32 wa, wb;
        const float* __restrict__ wp0 = WT + j;
        CLDW64
        GGRP(0, 0) GGRP(4, 0) GGRP(8, 0) GGRP(12, 0)
    }
    if constexpr (K == 128) {  // k-half 1: k in [64,128)
        vf32 wa, wb;
        const float* __restrict__ wp0 = WT + (long)64 * G4 + j;
        CLDW64
        GGRP(0, 64) GGRP(4, 64) GGRP(8, 64) GGRP(12, 64)
    }

#pragma unroll
    for (int r = 0; r < 16; ++r) gb[(long)r * gstride] = acc[r];
}

// ----------------------------------------------------------------------------
// LSTM scan. One block per batch element (grid=256 = 1 block/CU), 1024
// threads (16 waves, 4/EU). Thread = (half, row): row in [0,512) owns gate
// row `row`, half selects k in [half*64, half*64+64). 64 weights/thread in
// two SSA vf32 -> ~90 VGPRs, under the 128 budget pinned by
// amdgpu_waves_per_eu(4,4). Split-k partials merge via LDS; 3 barriers/step.
// (R3-R5: 128 weights/thread was force-spilled by the RA at VGPR_Count=76 ->
// ~4000 cyc/step L2-scratch-bound.)
// ----------------------------------------------------------------------------
#define SDOT2(q) { float hq0 = RL(hreg, q); float hq1 = RL(hreg, (q)+1); \
                   g0 = fmaf(hq0, WG2(q),     g0); \
                   g1 = fmaf(hq1, WG2((q)+1), g1); }
#define SDOT8(q)  SDOT2(q) SDOT2((q)+2) SDOT2((q)+4) SDOT2((q)+6)
#define SDOT32(q) SDOT8(q) SDOT8((q)+8) SDOT8((q)+16) SDOT8((q)+24)

__global__ __launch_bounds__(1024) __attribute__((amdgpu_waves_per_eu(4, 4)))
void lstm_scan(const float* __restrict__ gx, const float* __restrict__ Whh,
               float* __restrict__ h_state, float* __restrict__ c_state,
               float* __restrict__ h1c,     /* null for layer 1 */
               float* __restrict__ h2last,  /* null for layer 0 */
               int Tc, int storeLast)
{
    __shared__ float h_sh[H];
    __shared__ float partial[G4];
    __shared__ float gates[G4];

    const int tid  = threadIdx.x;
    const int b    = blockIdx.x;
    const int lane = tid & 63;
    const int half = tid >> 9;        // 0: k in [0,64), 1: k in [64,128)
    const int row  = tid & 511;       // gate row

    vf32 wa, wb;
    {
        const float* __restrict__ wp = Whh + (long)row * H + (half << 6);
#pragma unroll
        for (int q = 0; q < 64; q += 4) {
            float4 t4 = *(const float4*)(wp + q);
            WS2(q + 0, t4.x); WS2(q + 1, t4.y); WS2(q + 2, t4.z); WS2(q + 3, t4.w);
        }
    }

    float c = 0.f;
    if (tid < H) { h_sh[tid] = h_state[b * H + tid]; c = c_state[b * H + tid]; }
    __syncthreads();
    float hreg = h_sh[(half << 6) + lane];

    const long gstride = (long)B * G4;
    const float* __restrict__ gxp = gx + (long)b * G4 + row;
    float gc = 0.f, gn = 0.f;
    if (half == 0) {
        gc = gxp[0];
        gn = (Tc > 1) ? gxp[gstride] : 0.f;
    }

    for (int t = 0; t < Tc; ++t) {
        float gn2 = (half == 0 && t + 2 < Tc) ? gxp[(long)(t + 2) * gstride] : 0.f;

        float g0 = 0.f, g1 = 0.f;
        SDOT32(0) SDOT32(32)
        float s = g0 + g1;

        if (half) partial[row] = s;
        __syncthreads();

        if (half == 0) {
            float g = gc + s + partial[row];
            // rows [0,256) = i,f (sigmoid); [256,384) = g (tanh); [384,512) = o (sigmoid)
            float act = (row < 2 * H || row >= 3 * H) ? 1.f / (1.f + expf(-g)) : tanhf(g);
            gates[row] = act;
        }
        __syncthreads();

        if (tid < H) {
            float iv = gates[tid], fv = gates[H + tid], gv = gates[2 * H + tid], ov = gates[3 * H + tid];
            c = fmaf(fv, c, iv * gv);
            float hn = ov * tanhf(c);
            h_sh[tid] = hn;
            if (h1c) h1c[(long)b * Tc * H + (long)t * H + tid] = hn;
            if (storeLast && t == Tc - 1) h2last[b * H + tid] = hn;
        }
        __syncthreads();
        hreg = h_sh[(half << 6) + lane];
        gc = gn; gn = gn2;
    }

    if (tid < H) { h_state[b * H + tid] = h_sh[tid]; c_state[b * H + tid] = c; }
}

// ----------------------------------------------------------------------------
// Dropout: JAX threefry2x32, jax_threefry_partitionable=True (default since
// jax 0.4.36): counter (0, e), bits = y0 ^ y1, key (0, 42).
// ----------------------------------------------------------------------------
__device__ __forceinline__ uint32_t rotl32(uint32_t x, int r) { return (x << r) | (x >> (32 - r)); }

__global__ void dropout_kernel(const float* __restrict__ h2last, float* __restrict__ h2drop)
{
    int e = blockIdx.x * blockDim.x + threadIdx.x;
    if (e >= B * H) return;
    const uint32_t k0 = 0u, k1 = 42u, k2 = 0u ^ 42u ^ 0x1BD11BDAu;
    uint32_t x0 = 0u;
    uint32_t x1 = (uint32_t)e;
    x0 += k0; x1 += k1;
#define RG(ra,rb,rc,rd,ka,kb,inc) \
    x0 += x1; x1 = rotl32(x1, ra); x1 ^= x0; \
    x0 += x1; x1 = rotl32(x1, rb); x1 ^= x0; \
    x0 += x1; x1 = rotl32(x1, rc); x1 ^= x0; \
    x0 += x1; x1 = rotl32(x1, rd); x1 ^= x0; \
    x0 += ka; x1 += kb + inc;
    RG(13,15,26, 6, k1, k2, 1u)
    RG(17,29,16,24, k2, k0, 2u)
    RG(13,15,26, 6, k0, k1, 3u)
    RG(17,29,16,24, k1, k2, 4u)
    RG(13,15,26, 6, k2, k0, 5u)
#undef RG
    uint32_t bits = x0 ^ x1;
    float u = __uint_as_float((bits >> 9) | 0x3f800000u) - 1.0f;
    float a = h2last[e];
    h2drop[e] = (u >= 0.3f) ? (a / 0.7f) : 0.0f;
}

// ----------------------------------------------------------------------------
// Head: out[b][n] = b_out[n] + sum_u h2drop[b][u] * W_out[n][u]
// ----------------------------------------------------------------------------
__global__ void out_kernel(const float* __restrict__ h2drop, const float* __restrict__ W_out,
                           const float* __restrict__ b_out, float* __restrict__ out)
{
    int i = blockIdx.x * blockDim.x + threadIdx.x;
    if (i >= B * 2) return;
    int bb = i >> 1, n = i & 1;
    float acc = b_out[n];
    const float* __restrict__ hp = h2drop + (long)bb * H;
    const float* __restrict__ wp = W_out + (long)n * H;
#pragma unroll 4
    for (int u = 0; u < H; ++u) acc = fmaf(hp[u], wp[u], acc);
    out[i] = acc;
}

// ----------------------------------------------------------------------------
extern "C" void kernel_launch(void* const* d_in, const int* in_sizes, int n_in,
                              void* d_out, int out_size, void* d_ws, size_t ws_size,
                              hipStream_t stream)
{
    const float* x     = (const float*)d_in[0];
    const float* W_ih0 = (const float*)d_in[1];
    const float* W_hh0 = (const float*)d_in[2];
    const float* b_ih0 = (const float*)d_in[3];
    const float* b_hh0 = (const float*)d_in[4];
    const float* W_ih1 = (const float*)d_in[5];
    const float* W_hh1 = (const float*)d_in[6];
    const float* b_ih1 = (const float*)d_in[7];
    const float* b_hh1 = (const float*)d_in[8];
    const float* W_out = (const float*)d_in[9];
    const float* b_out = (const float*)d_in[10];
    float* out = (float*)d_out;

    char* ws = (char*)d_ws;
    size_t off = 0;
    auto alloc = [&](size_t bytes) { void* p = ws + off; off += (bytes + 255) & ~255ull; return p; };

    float* WT0    = (float*)alloc((size_t)FIN * G4 * 4);
    float* WT1    = (float*)alloc((size_t)H * G4 * 4);
    float* bsum0  = (float*)alloc((size_t)G4 * 4);
    float* bsum1  = (float*)alloc((size_t)G4 * 4);
    float* states = (float*)alloc((size_t)4 * B * H * 4);
    float* h0s = states, *c0s = states + B * H, *h1s = states + 2 * B * H, *c1s = states + 3 * B * H;
    float* h2last = (float*)alloc((size_t)B * H * 4);
    float* h2drop = (float*)alloc((size_t)B * H * 4);

    size_t fixed = off;
    int Tc = 16;
    const int cands[7] = {1024, 512, 256, 128, 64, 32, 16};
    for (int ci = 0; ci < 7; ++ci) {
        size_t need = fixed + (size_t)cands[ci] * ((size_t)B * H * 4 + (size_t)B * G4 * 4) + 8192;
        if (need <= ws_size) { Tc = cands[ci]; break; }
    }
    float* h1c = (float*)alloc((size_t)B * Tc * H * 4);
    float* gxb = (float*)alloc((size_t)Tc * B * G4 * 4);

    fprintf(stderr, "[kernel_launch] ws_size=%zu fixed=%zu Tc=%d total_used=%zu\n",
            ws_size, fixed, Tc, off);

    prep_kernel<<<512, 256, 0, stream>>>(W_ih0, b_ih0, b_hh0, W_ih1, b_ih1, b_hh1,
                                         WT0, WT1, bsum0, bsum1, states);

    const int nch = T / Tc;
    for (int c = 0; c < nch; ++c) {
        int t0 = c * Tc;
        gemm_gx<FIN><<<(B * Tc) / 16, 512, 0, stream>>>(x, (long)T * FIN, (long)FIN, t0,
                                                        WT0, bsum0, gxb, Tc);
        lstm_scan<<<B, 1024, 0, stream>>>(gxb, W_hh0, h0s, c0s, h1c, nullptr, Tc, 0);
        gemm_gx<H><<<(B * Tc) / 16, 512, 0, stream>>>(h1c, (long)Tc * H, (long)H, 0,
                                                      WT1, bsum1, gxb, Tc);
        lstm_scan<<<B, 1024, 0, stream>>>(gxb, W_hh1, h1s, c1s, nullptr, h2last, Tc,
                                          (t0 + Tc == T) ? 1 : 0);
    }

    dropout_kernel<<<128, 256, 0, stream>>>(h2last, h2drop);
    out_kernel<<<2, 256, 0, stream>>>(h2drop, W_out, b_out, out);
}